// Round 1
// baseline (427.131 us; speedup 1.0000x reference)
//
#include <hip/hip_runtime.h>

#define HH 1024
#define WW 1024
#define NB 8
constexpr int PLANE = HH * WW;
constexpr int TOTAL = NB * PLANE;

__device__ __forceinline__ int clampi(int v, int lo, int hi) {
    return v < lo ? lo : (v > hi ? hi : v);
}

// insertion sort N elements, return a[r]
template <int N>
__device__ __forceinline__ float rank_select(float* a, int r) {
#pragma unroll
    for (int i = 1; i < N; ++i) {
        float key = a[i];
        int j = i - 1;
        while (j >= 0 && a[j] > key) {
            a[j + 1] = a[j];
            --j;
        }
        a[j + 1] = key;
    }
    return a[r];
}

__global__ void demosaick_kernel(const float* __restrict__ img, float* __restrict__ dst) {
    int idx = blockIdx.x * blockDim.x + threadIdx.x;
    if (idx >= TOTAL) return;
    int b = idx / PLANE;
    int p = idx - b * PLANE;
    int y = p / WW, x = p - (p / WW) * WW;
    const float* im = img + b * PLANE;
    float accR = 0.f, accG = 0.f, accB = 0.f;
#pragma unroll
    for (int dy = -1; dy <= 1; ++dy) {
        int cy = clampi(y + dy, 0, HH - 1);
        int ady = dy < 0 ? -dy : dy;
#pragma unroll
        for (int dx = -1; dx <= 1; ++dx) {
            int cx = clampi(x + dx, 0, WW - 1);
            int adx = dx < 0 ? -dx : dx;
            float v = im[cy * WW + cx];
            // KRB/4 weight = (2-|dy|)*(2-|dx|)/4 ; KG/4 weight = 1 center, 0.25 plus, 0 corner
            float wrb = 0.25f * (float)((2 - ady) * (2 - adx));
            float wg = (ady + adx == 0) ? 1.0f : ((ady + adx == 1) ? 0.25f : 0.0f);
            bool is_r = ((cy & 1) == 0) && ((cx & 1) == 1);
            bool is_b = ((cy & 1) == 1) && ((cx & 1) == 0);
            if (is_r)
                accR += wrb * v;
            else if (is_b)
                accB += wrb * v;
            else
                accG += wg * v;
        }
    }
    float* o = dst + (size_t)b * 3 * PLANE;
    o[0 * PLANE + p] = accR;
    o[1 * PLANE + p] = accG;
    o[2 * PLANE + p] = accB;
}

// Pass A: Rnew = median8(R-G)+G ; Bnew = median8(B-G)+G.  Writes dst R,B planes.
__global__ void rb_kernel(const float* __restrict__ src, float* __restrict__ dst) {
    int idx = blockIdx.x * blockDim.x + threadIdx.x;
    if (idx >= TOTAL) return;
    int b = idx / PLANE;
    int p = idx - b * PLANE;
    int y = p / WW, x = p - (p / WW) * WW;
    const float* R = src + (size_t)b * 3 * PLANE;
    const float* G = R + PLANE;
    const float* Bp = R + 2 * PLANE;
    float g0 = G[p];
    float dR[8], dB[8];
    int k = 0;
#pragma unroll
    for (int dy = -1; dy <= 1; ++dy) {
        int cy = clampi(y + dy, 0, HH - 1);
#pragma unroll
        for (int dx = -1; dx <= 1; ++dx) {
            if (dy == 0 && dx == 0) continue;
            int cx = clampi(x + dx, 0, WW - 1);
            int q = cy * WW + cx;
            float gv = G[q];
            dR[k] = R[q] - gv;
            dB[k] = Bp[q] - gv;
            ++k;
        }
    }
    float mR = rank_select<8>(dR, 4);
    float mB = rank_select<8>(dB, 4);
    float* o = dst + (size_t)b * 3 * PLANE;
    o[0 * PLANE + p] = mR + g0;
    o[2 * PLANE + p] = mB + g0;
}

// Pass B: Gnew = 0.5*(median4(G - Rnew) + median4(G - Bnew) + Rnew + Bnew)
// old G lives in src; Rnew/Bnew live in dst (written by rb_kernel); writes dst G plane.
__global__ void g_kernel(const float* __restrict__ src, float* __restrict__ dst) {
    int idx = blockIdx.x * blockDim.x + threadIdx.x;
    if (idx >= TOTAL) return;
    int b = idx / PLANE;
    int p = idx - b * PLANE;
    int y = p / WW, x = p - (p / WW) * WW;
    const float* Gold = src + (size_t)b * 3 * PLANE + PLANE;
    const float* Rn = dst + (size_t)b * 3 * PLANE;
    const float* Bn = Rn + 2 * PLANE;
    const int dys[4] = {-1, 0, 0, 1};
    const int dxs[4] = {0, -1, 1, 0};
    float dR[4], dB[4];
#pragma unroll
    for (int i = 0; i < 4; ++i) {
        int cy = clampi(y + dys[i], 0, HH - 1);
        int cx = clampi(x + dxs[i], 0, WW - 1);
        int q = cy * WW + cx;
        float gv = Gold[q];
        dR[i] = gv - Rn[q];
        dB[i] = gv - Bn[q];
    }
    float mR = rank_select<4>(dR, 2);
    float mB = rank_select<4>(dB, 2);
    float rn = Rn[p];
    float bn = Bn[p];
    float* o = dst + (size_t)b * 3 * PLANE;
    o[PLANE + p] = 0.5f * (mR + mB + rn + bn);
}

extern "C" void kernel_launch(void* const* d_in, const int* in_sizes, int n_in,
                              void* d_out, int out_size, void* d_ws, size_t ws_size,
                              hipStream_t stream) {
    const float* img = (const float*)d_in[0];
    float* out = (float*)d_out;
    float* ws = (float*)d_ws;

    dim3 block(256);
    dim3 grid((TOTAL + 255) / 256);

    // demosaick -> ws ; iter1 ws->out ; iter2 out->ws ; iter3 ws->out
    demosaick_kernel<<<grid, block, 0, stream>>>(img, ws);

    rb_kernel<<<grid, block, 0, stream>>>(ws, out);
    g_kernel<<<grid, block, 0, stream>>>(ws, out);

    rb_kernel<<<grid, block, 0, stream>>>(out, ws);
    g_kernel<<<grid, block, 0, stream>>>(out, ws);

    rb_kernel<<<grid, block, 0, stream>>>(ws, out);
    g_kernel<<<grid, block, 0, stream>>>(ws, out);
}